// Round 8
// baseline (629.289 us; speedup 1.0000x reference)
//
#include <hip/hip_runtime.h>
#include <math.h>

#define DIM     2048
#define NEXP    64
#define CAP     128
#define NTOK    8192
#define NTILE   256            // 256 gate tiles of 32 tokens
#define KC      128            // K-chunk staged in LDS (128 -> ~55 KB LDS, 2 blocks/CU)
#define NCH     (DIM/KC)       // 16 chunks
#define XWSTR   132            // row stride for xs/ws tiles (KC+4)
#define PSTR    68             // row stride for partial/logit tiles
#define RF      67108864       // floats per output region (S*E*C)
#define NFILL   2048           // fill blocks
#define GRID    (NTILE + NFILL)

typedef float vfloat4 __attribute__((ext_vector_type(4)));

// ---------------- 1. fused: gate GEMM (blocks 0..255) + zero-fill (256..2303)
// Gate: 512 thr, tile 32 tok x 64 exp, K sliced 16-way, both operands in LDS.
// Fill: 537 MB plain f4 stores. ~55 KB static LDS -> 2 blocks/CU, so a gate
// block (VALU/LDS-bound) and a fill block (VMEM store-bound) co-reside and
// overlap (m114: separate pipes co-schedule). Gate blocks first in the grid
// so the round-robin dispatch spreads them 1/CU early.
__global__ __launch_bounds__(512, 2) void fused_gate(
    const float* __restrict__ x, const float* __restrict__ wg,
    float* __restrict__ out,
    int* __restrict__ expert_idx, float* __restrict__ gate_top,
    int* __restrict__ rank,
    float* __restrict__ me_partial, int* __restrict__ counts)
{
    __shared__ __align__(16) float smem[(32 + NEXP) * XWSTR]; // 50,688 B
    __shared__ float me_w[8 * NEXP];
    __shared__ int   cnt_w[8 * NEXP];
    __shared__ int   exp_s[32];

    const int tid = threadIdx.x;
    const int b   = blockIdx.x;

    if (b >= NTILE) {
        // ---------------- fill branch: 2048 blocks x 512 thr x 32 f4 ----------
        const int zb = b - NTILE;
        vfloat4* o4 = reinterpret_cast<vfloat4*>(out);
        const vfloat4 z4 = {0.f, 0.f, 0.f, 0.f};
        size_t base = (size_t)zb * 16384 + tid;
        #pragma unroll
        for (int q = 0; q < 32; ++q)
            o4[base + ((size_t)q << 9)] = z4;
        if (zb == 0 && tid == 0)
            out[134217728ull] = 0.0f;  // the one float past the f4 span
        return;
    }

    // ---------------- gate branch ----------------
    float* xs = smem;                 // [32][XWSTR]
    float* ws = smem + 32 * XWSTR;    // [64][XWSTR]

    const int gb   = b;
    const int tok0 = gb * 32;
    const int sl   = tid >> 5;        // k-slice 0..15
    const int i    = tid & 31;
    const int tg   = i & 3;           // token group
    const int eg   = i >> 2;          // expert group 0..7
    const int kb   = sl * 8;          // slice's kk base within chunk

    float acc[8][8] = {};

    for (int ch = 0; ch < NCH; ++ch) {
        const int k0 = ch * KC;
        // stage x tile [32][128]: 1024 f4, 2 per thread, coalesced rows
        #pragma unroll
        for (int q = 0; q < 2; ++q) {
            int id = tid + (q << 9);
            int r = id >> 5, c = id & 31;
            float4 v = *(const float4*)(x + (size_t)(tok0 + r) * DIM + k0 + 4 * c);
            *(float4*)(&xs[r * XWSTR + 4 * c]) = v;
        }
        // stage w tile [64][128]: 2048 f4, 4 per thread
        #pragma unroll
        for (int q = 0; q < 4; ++q) {
            int id = tid + (q << 9);
            int r = id >> 5, c = id & 31;
            float4 v = *(const float4*)(wg + (size_t)r * DIM + k0 + 4 * c);
            *(float4*)(&ws[r * XWSTR + 4 * c]) = v;
        }
        __syncthreads();

        #pragma unroll
        for (int q2 = 0; q2 < 2; ++q2) {        // 2 x 4-kk steps = 8 kk/slice
            const int kk = kb + 4 * q2;
            float4 xt[8], we[8];
            #pragma unroll
            for (int j = 0; j < 8; ++j)
                xt[j] = *(const float4*)(&xs[(tg + 4 * j) * XWSTR + kk]);
            #pragma unroll
            for (int m = 0; m < 8; ++m)
                we[m] = *(const float4*)(&ws[(eg + 8 * m) * XWSTR + kk]);
            #pragma unroll
            for (int j = 0; j < 8; ++j)
                #pragma unroll
                for (int m = 0; m < 8; ++m) {
                    acc[j][m] = fmaf(xt[j].x, we[m].x, acc[j][m]);
                    acc[j][m] = fmaf(xt[j].y, we[m].y, acc[j][m]);
                    acc[j][m] = fmaf(xt[j].z, we[m].z, acc[j][m]);
                    acc[j][m] = fmaf(xt[j].w, we[m].w, acc[j][m]);
                }
        }
        __syncthreads();
    }

    // ---- reduce 16 k-slices in a 4-round cascade (fits 50 KB LDS) ----
    float* part = smem;                 // [4][32][PSTR] = 8704 floats
    float* lgt  = smem + 4 * 32 * PSTR; // [32][PSTR]   = 2176 floats
    if (sl >= 12) {
        #pragma unroll
        for (int j = 0; j < 8; ++j)
            #pragma unroll
            for (int m = 0; m < 8; ++m)
                part[((sl - 12) * 32 + tg + 4 * j) * PSTR + eg + 8 * m] = acc[j][m];
    }
    __syncthreads();
    if (sl >= 8 && sl < 12) {
        #pragma unroll
        for (int j = 0; j < 8; ++j)
            #pragma unroll
            for (int m = 0; m < 8; ++m)
                part[((sl - 8) * 32 + tg + 4 * j) * PSTR + eg + 8 * m] += acc[j][m];
    }
    __syncthreads();
    if (sl >= 4 && sl < 8) {
        #pragma unroll
        for (int j = 0; j < 8; ++j)
            #pragma unroll
            for (int m = 0; m < 8; ++m)
                part[((sl - 4) * 32 + tg + 4 * j) * PSTR + eg + 8 * m] += acc[j][m];
    }
    __syncthreads();
    if (sl < 4) {
        #pragma unroll
        for (int j = 0; j < 8; ++j)
            #pragma unroll
            for (int m = 0; m < 8; ++m)
                part[(sl * 32 + tg + 4 * j) * PSTR + eg + 8 * m] += acc[j][m];
    }
    __syncthreads();

    {   // final 4-slice reduction: thread -> (row t, 4 experts)
        int t  = tid >> 4;
        int e0 = (tid & 15) << 2;
        float4 a = {0, 0, 0, 0};
        #pragma unroll
        for (int s2 = 0; s2 < 4; ++s2) {
            float4 p = *(const float4*)(&part[(s2 * 32 + t) * PSTR + e0]);
            a.x += p.x; a.y += p.y; a.z += p.z; a.w += p.w;
        }
        *(float4*)(&lgt[t * PSTR + e0]) = a;   // lgt disjoint from part
    }
    __syncthreads();

    // ---- softmax + argmax: 8 waves x 4 rows, lane = expert ----
    const int lane = tid & 63;
    const int wv   = tid >> 6;
    float me_acc  = 0.0f;
    int   cnt_acc = 0;
    #pragma unroll
    for (int r4 = 0; r4 < 4; ++r4) {
        int row = wv * 4 + r4;
        float v = lgt[row * PSTR + lane];
        float m = v; int mi = lane;
        #pragma unroll
        for (int off = 32; off > 0; off >>= 1) {
            float om  = __shfl_xor(m, off);
            int   omi = __shfl_xor(mi, off);
            if (om > m || (om == m && omi < mi)) { m = om; mi = omi; }
        }
        float ex = __expf(v - m);
        float sm = ex;
        #pragma unroll
        for (int off = 32; off > 0; off >>= 1) sm += __shfl_xor(sm, off);
        me_acc += ex / sm;
        if (lane == mi) {
            expert_idx[tok0 + row] = mi;
            gate_top[tok0 + row]   = 1.0f / sm;
            exp_s[row] = mi;
            ++cnt_acc;
        }
    }
    me_w[wv * NEXP + lane]  = me_acc;
    cnt_w[wv * NEXP + lane] = cnt_acc;
    __syncthreads();

    if (tid < 32) {  // within-tile rank (token order)
        int e = exp_s[tid];
        int rk = 0;
        for (int u = 0; u < tid; ++u) rk += (exp_s[u] == e) ? 1 : 0;
        rank[tok0 + tid] = rk;
    }
    if (tid < NEXP) {
        float ms = 0.f; int cs = 0;
        #pragma unroll
        for (int w = 0; w < 8; ++w) { ms += me_w[w * NEXP + tid]; cs += cnt_w[w * NEXP + tid]; }
        me_partial[gb * NEXP + tid] = ms;
        counts[gb * NEXP + tid]     = cs;
    }
}

// ---------------- 2. prefix + l_aux + direct scatter (R7, unchanged) --------
__global__ __launch_bounds__(1024) void prefix_laux(
    const float* __restrict__ me_partial, const int* __restrict__ counts,
    const int* __restrict__ expert_idx, const int* __restrict__ rank,
    const float* __restrict__ gate_top, float* __restrict__ out)
{
    __shared__ int   bo_l[NTILE * NEXP];   // 64 KB exclusive offsets
    __shared__ int   cnt_l[16 * NEXP];
    __shared__ float me_l[16 * NEXP];
    __shared__ int   cnt_tot[NEXP];
    __shared__ float me_tot[NEXP];

    const int tid = threadIdx.x;
    const int e   = tid & 63;
    const int g   = tid >> 6;          // 0..15

    int cs = 0; float ms = 0.f;
    #pragma unroll
    for (int i = 0; i < 16; ++i) {
        int t = g * 16 + i;
        cs += counts[t * NEXP + e];
        ms += me_partial[t * NEXP + e];
    }
    cnt_l[g * NEXP + e] = cs;
    me_l[g * NEXP + e]  = ms;
    __syncthreads();

    if (g == 0) {
        int run = 0; float mt = 0.f;
        #pragma unroll
        for (int i = 0; i < 16; ++i) {
            int c = cnt_l[i * NEXP + e];
            cnt_l[i * NEXP + e] = run;
            run += c;
            mt  += me_l[i * NEXP + e];
        }
        cnt_tot[e] = run;
        me_tot[e]  = mt;
    }
    __syncthreads();

    int run = cnt_l[g * NEXP + e];
    #pragma unroll
    for (int i = 0; i < 16; ++i) {
        int t = g * 16 + i;
        bo_l[t * NEXP + e] = run;
        run += counts[t * NEXP + e];
    }
    __syncthreads();

    if (tid < NEXP) {
        float v = (me_tot[e] / (float)NTOK) * ((float)cnt_tot[e] / (float)NTOK);
        #pragma unroll
        for (int off = 32; off > 0; off >>= 1) v += __shfl_xor(v, off);
        if (e == 0) out[0] = v * (float)NEXP;   // mean(me*ce)*E*E == sum*E
    }

    #pragma unroll
    for (int ii = 0; ii < 8; ++ii) {           // direct scatter of nonzeros
        int s  = tid + (ii << 10);
        int ex = expert_idx[s];
        int loc = bo_l[(s >> 5) * NEXP + ex] + rank[s];
        if (loc < CAP) {
            size_t off = 1 + (size_t)s * (NEXP * CAP) + (size_t)ex * CAP + loc;
            out[off]              = gate_top[s];   // combine
            out[off + (size_t)RF] = 1.0f;          // dispatch
        }
    }
}

extern "C" void kernel_launch(void* const* d_in, const int* in_sizes, int n_in,
                              void* d_out, int out_size, void* d_ws, size_t ws_size,
                              hipStream_t stream)
{
    const float* x  = (const float*)d_in[0];
    const float* wg = (const float*)d_in[1];
    float* out = (float*)d_out;

    char* ws = (char*)d_ws;
    int*   expert_idx = (int*)  (ws);             // 32 KB
    float* gate_top   = (float*)(ws + 32768);     // 32 KB
    int*   rank       = (int*)  (ws + 65536);     // 32 KB
    float* me_partial = (float*)(ws + 98304);     // 64 KB
    int*   counts     = (int*)  (ws + 163840);    // 64 KB  (total 224 KB)

    fused_gate<<<GRID, 512, 0, stream>>>(x, wg, out, expert_idx, gate_top,
                                         rank, me_partial, counts);
    prefix_laux<<<1, 1024, 0, stream>>>(me_partial, counts, expert_idx, rank,
                                        gate_top, out);
}

// Round 9
// 614.490 us; speedup vs baseline: 1.0241x; 1.0241x over previous
//
#include <hip/hip_runtime.h>
#include <math.h>

#define DIM     2048
#define NEXP    64
#define CAP     128
#define NTOK    8192
#define NTILE   256            // 256 tiles of 32 tokens
#define KC      256            // K-chunk staged in LDS
#define NCH     (DIM/KC)       // 8 chunks
#define XWSTR   260            // row stride for xs/ws tiles (KC+4)
#define PSTR    68             // row stride for partial/logit tiles
#define RF      67108864       // floats per output region (S*E*C)

// ---------------- 1. gate GEMM + softmax + argmax + rank (R6/R7, proven) ----
__global__ __launch_bounds__(512, 2) void gate_kernel(
    const float* __restrict__ x, const float* __restrict__ wg,
    int* __restrict__ expert_idx, float* __restrict__ gate_top,
    int* __restrict__ rank,
    float* __restrict__ me_partial, int* __restrict__ counts)
{
    __shared__ __align__(16) float smem[(32 + NEXP) * XWSTR]; // 99,840 B
    __shared__ float me_w[8 * NEXP];
    __shared__ int   cnt_w[8 * NEXP];
    __shared__ int   exp_s[32];

    float* xs = smem;                 // [32][XWSTR]
    float* ws = smem + 32 * XWSTR;    // [64][XWSTR]

    const int tid  = threadIdx.x;
    const int gb   = blockIdx.x;
    const int tok0 = gb * 32;
    const int sl   = tid >> 5;        // k-slice 0..15
    const int i    = tid & 31;
    const int tg   = i & 3;           // token group
    const int eg   = i >> 2;          // expert group 0..7
    const int kb   = sl * 16;         // slice's kk base within chunk

    float acc[8][8] = {};

    for (int ch = 0; ch < NCH; ++ch) {
        const int k0 = ch * KC;
        #pragma unroll
        for (int q = 0; q < 4; ++q) {
            int id = tid + (q << 9);
            int r = id >> 6, c = id & 63;
            float4 v = *(const float4*)(x + (size_t)(tok0 + r) * DIM + k0 + 4 * c);
            *(float4*)(&xs[r * XWSTR + 4 * c]) = v;
        }
        #pragma unroll
        for (int q = 0; q < 8; ++q) {
            int id = tid + (q << 9);
            int r = id >> 6, c = id & 63;
            float4 v = *(const float4*)(wg + (size_t)r * DIM + k0 + 4 * c);
            *(float4*)(&ws[r * XWSTR + 4 * c]) = v;
        }
        __syncthreads();

        #pragma unroll
        for (int q2 = 0; q2 < 4; ++q2) {
            const int kk = kb + 4 * q2;
            float4 xt[8], we[8];
            #pragma unroll
            for (int j = 0; j < 8; ++j)
                xt[j] = *(const float4*)(&xs[(tg + 4 * j) * XWSTR + kk]);
            #pragma unroll
            for (int m = 0; m < 8; ++m)
                we[m] = *(const float4*)(&ws[(eg + 8 * m) * XWSTR + kk]);
            #pragma unroll
            for (int j = 0; j < 8; ++j)
                #pragma unroll
                for (int m = 0; m < 8; ++m) {
                    acc[j][m] = fmaf(xt[j].x, we[m].x, acc[j][m]);
                    acc[j][m] = fmaf(xt[j].y, we[m].y, acc[j][m]);
                    acc[j][m] = fmaf(xt[j].z, we[m].z, acc[j][m]);
                    acc[j][m] = fmaf(xt[j].w, we[m].w, acc[j][m]);
                }
        }
        __syncthreads();
    }

    float* part = smem;                 // [8][32][PSTR]
    float* lgt  = smem + 8 * 32 * PSTR; // [32][PSTR]
    if (sl >= 8) {
        #pragma unroll
        for (int j = 0; j < 8; ++j)
            #pragma unroll
            for (int m = 0; m < 8; ++m)
                part[((sl - 8) * 32 + tg + 4 * j) * PSTR + eg + 8 * m] = acc[j][m];
    }
    __syncthreads();
    if (sl < 8) {
        #pragma unroll
        for (int j = 0; j < 8; ++j)
            #pragma unroll
            for (int m = 0; m < 8; ++m) {
                int idx = (sl * 32 + tg + 4 * j) * PSTR + eg + 8 * m;
                part[idx] += acc[j][m];
            }
    }
    __syncthreads();

    {
        int t  = tid >> 4;
        int e0 = (tid & 15) << 2;
        float4 a = {0, 0, 0, 0};
        #pragma unroll
        for (int s2 = 0; s2 < 8; ++s2) {
            float4 p = *(const float4*)(&part[(s2 * 32 + t) * PSTR + e0]);
            a.x += p.x; a.y += p.y; a.z += p.z; a.w += p.w;
        }
        *(float4*)(&lgt[t * PSTR + e0]) = a;
    }
    __syncthreads();

    const int lane = tid & 63;
    const int wv   = tid >> 6;
    float me_acc  = 0.0f;
    int   cnt_acc = 0;
    #pragma unroll
    for (int r4 = 0; r4 < 4; ++r4) {
        int row = wv * 4 + r4;
        float v = lgt[row * PSTR + lane];
        float m = v; int mi = lane;
        #pragma unroll
        for (int off = 32; off > 0; off >>= 1) {
            float om  = __shfl_xor(m, off);
            int   omi = __shfl_xor(mi, off);
            if (om > m || (om == m && omi < mi)) { m = om; mi = omi; }
        }
        float ex = __expf(v - m);
        float sm = ex;
        #pragma unroll
        for (int off = 32; off > 0; off >>= 1) sm += __shfl_xor(sm, off);
        me_acc += ex / sm;
        if (lane == mi) {
            expert_idx[tok0 + row] = mi;
            gate_top[tok0 + row]   = 1.0f / sm;
            exp_s[row] = mi;
            ++cnt_acc;
        }
    }
    me_w[wv * NEXP + lane]  = me_acc;
    cnt_w[wv * NEXP + lane] = cnt_acc;
    __syncthreads();

    if (tid < 32) {
        int e = exp_s[tid];
        int rk = 0;
        for (int u = 0; u < tid; ++u) rk += (exp_s[u] == e) ? 1 : 0;
        rank[tok0 + tid] = rk;
    }
    if (tid < NEXP) {
        float ms = 0.f; int cs = 0;
        #pragma unroll
        for (int w = 0; w < 8; ++w) { ms += me_w[w * NEXP + tid]; cs += cnt_w[w * NEXP + tid]; }
        me_partial[gb * NEXP + tid] = ms;
        counts[gb * NEXP + tid]     = cs;
    }
}

// ---------------- 2. prefix + l_aux + direct scatter (R7, unchanged) --------
__global__ __launch_bounds__(1024) void prefix_laux(
    const float* __restrict__ me_partial, const int* __restrict__ counts,
    const int* __restrict__ expert_idx, const int* __restrict__ rank,
    const float* __restrict__ gate_top, float* __restrict__ out)
{
    __shared__ int   bo_l[NTILE * NEXP];   // 64 KB exclusive offsets
    __shared__ int   cnt_l[16 * NEXP];
    __shared__ float me_l[16 * NEXP];
    __shared__ int   cnt_tot[NEXP];
    __shared__ float me_tot[NEXP];

    const int tid = threadIdx.x;
    const int e   = tid & 63;
    const int g   = tid >> 6;          // 0..15

    int cs = 0; float ms = 0.f;
    #pragma unroll
    for (int i = 0; i < 16; ++i) {
        int t = g * 16 + i;
        cs += counts[t * NEXP + e];
        ms += me_partial[t * NEXP + e];
    }
    cnt_l[g * NEXP + e] = cs;
    me_l[g * NEXP + e]  = ms;
    __syncthreads();

    if (g == 0) {
        int run = 0; float mt = 0.f;
        #pragma unroll
        for (int i = 0; i < 16; ++i) {
            int c = cnt_l[i * NEXP + e];
            cnt_l[i * NEXP + e] = run;
            run += c;
            mt  += me_l[i * NEXP + e];
        }
        cnt_tot[e] = run;
        me_tot[e]  = mt;
    }
    __syncthreads();

    int run = cnt_l[g * NEXP + e];
    #pragma unroll
    for (int i = 0; i < 16; ++i) {
        int t = g * 16 + i;
        bo_l[t * NEXP + e] = run;
        run += counts[t * NEXP + e];
    }
    __syncthreads();

    if (tid < NEXP) {
        float v = (me_tot[e] / (float)NTOK) * ((float)cnt_tot[e] / (float)NTOK);
        #pragma unroll
        for (int off = 32; off > 0; off >>= 1) v += __shfl_xor(v, off);
        if (e == 0) out[0] = v * (float)NEXP;   // mean(me*ce)*E*E == sum*E
    }

    #pragma unroll
    for (int ii = 0; ii < 8; ++ii) {           // direct scatter of nonzeros
        int s  = tid + (ii << 10);
        int ex = expert_idx[s];
        int loc = bo_l[(s >> 5) * NEXP + ex] + rank[s];
        if (loc < CAP) {
            size_t off = 1 + (size_t)s * (NEXP * CAP) + (size_t)ex * CAP + loc;
            out[off]              = gate_top[s];   // combine
            out[off + (size_t)RF] = 1.0f;          // dispatch
        }
    }
}

extern "C" void kernel_launch(void* const* d_in, const int* in_sizes, int n_in,
                              void* d_out, int out_size, void* d_ws, size_t ws_size,
                              hipStream_t stream)
{
    const float* x  = (const float*)d_in[0];
    const float* wg = (const float*)d_in[1];
    float* out = (float*)d_out;

    char* ws = (char*)d_ws;
    int*   expert_idx = (int*)  (ws);             // 32 KB
    float* gate_top   = (float*)(ws + 32768);     // 32 KB
    int*   rank       = (int*)  (ws + 65536);     // 32 KB
    float* me_partial = (float*)(ws + 98304);     // 64 KB
    int*   counts     = (int*)  (ws + 163840);    // 64 KB  (total 224 KB)

    // Vendor fill (fillBufferAligned): proven 6.3 TB/s on this device every
    // iteration, vs ~2.5-3 TB/s inferred for all four of our hand-rolled
    // fill variants (R5-R8). Stream-ordered + graph-capture-safe.
    hipMemsetAsync(d_out, 0, (size_t)out_size * sizeof(float), stream);

    gate_kernel<<<NTILE, 512, 0, stream>>>(x, wg, expert_idx, gate_top, rank,
                                           me_partial, counts);
    prefix_laux<<<1, 1024, 0, stream>>>(me_partial, counts, expert_idx, rank,
                                        gate_top, out);
}

// Round 10
// 591.249 us; speedup vs baseline: 1.0643x; 1.0393x over previous
//
#include <hip/hip_runtime.h>
#include <math.h>

#define DIM     2048
#define NEXP    64
#define CAP     128
#define NTOK    8192
#define NTILE   256            // 256 tiles of 32 tokens
#define KC      256            // K-chunk staged in LDS
#define NCH     (DIM/KC)       // 8 chunks
#define XWSTR   260            // row stride for xs/ws tiles (KC+4)
#define PSTR    68             // row stride for partial/logit tiles
#define RF      67108864       // floats per output region (S*E*C)

typedef float vfloat4 __attribute__((ext_vector_type(4)));

// ---- 1. gate GEMM + interleaved zero-fill + softmax/argmax/rank ----
// R9's proven gate (KC=256, 512 thr, both operands LDS) with the 537 MB
// zero-fill folded in: 32 NT f4 stores per thread per chunk, issued AFTER
// the staging loads (vmcnt retires in order -> ds_write waits only on the
// older load). The per-chunk barrier drain of the stores IS the HBM write
// wall; the GEMM hides inside it instead of running serially after it.
__global__ __launch_bounds__(512, 2) void gate_fill(
    const float* __restrict__ x, const float* __restrict__ wg,
    float* __restrict__ out,
    int* __restrict__ expert_idx, float* __restrict__ gate_top,
    int* __restrict__ rank,
    float* __restrict__ me_partial, int* __restrict__ counts)
{
    __shared__ __align__(16) float smem[(32 + NEXP) * XWSTR]; // 99,840 B
    __shared__ float me_w[8 * NEXP];
    __shared__ int   cnt_w[8 * NEXP];
    __shared__ int   exp_s[32];

    float* xs = smem;                 // [32][XWSTR]
    float* ws = smem + 32 * XWSTR;    // [64][XWSTR]

    const int tid  = threadIdx.x;
    const int gb   = blockIdx.x;
    const int tok0 = gb * 32;
    const int sl   = tid >> 5;        // k-slice 0..15
    const int i    = tid & 31;
    const int tg   = i & 3;           // token group
    const int eg   = i >> 2;          // expert group 0..7
    const int kb   = sl * 16;         // slice's kk base within chunk

    vfloat4* o4 = reinterpret_cast<vfloat4*>(out);
    const vfloat4 z4 = {0.f, 0.f, 0.f, 0.f};

    if (gb == 0 && tid == 0)
        out[134217728ull] = 0.0f;     // the one float past the f4 span

    float acc[8][8] = {};

    for (int ch = 0; ch < NCH; ++ch) {
        const int k0 = ch * KC;
        // staging loads FIRST (critical path)...
        #pragma unroll
        for (int q = 0; q < 4; ++q) {
            int id = tid + (q << 9);
            int r = id >> 6, c = id & 63;
            float4 v = *(const float4*)(x + (size_t)(tok0 + r) * DIM + k0 + 4 * c);
            *(float4*)(&xs[r * XWSTR + 4 * c]) = v;
        }
        #pragma unroll
        for (int q = 0; q < 8; ++q) {
            int id = tid + (q << 9);
            int r = id >> 6, c = id & 63;
            float4 v = *(const float4*)(wg + (size_t)r * DIM + k0 + 4 * c);
            *(float4*)(&ws[r * XWSTR + 4 * c]) = v;
        }
        // ...then this chunk's slice of the zero-fill (independent stores;
        // they drain during/after the inner loop, at the barrier).
        {
            size_t base = (size_t)gb * 131072 + (size_t)(ch << 14) + tid;
            #pragma unroll
            for (int q = 0; q < 32; ++q)
                __builtin_nontemporal_store(z4, &o4[base + (size_t)(q << 9)]);
        }
        __syncthreads();

        #pragma unroll
        for (int q2 = 0; q2 < 4; ++q2) {
            const int kk = kb + 4 * q2;
            float4 xt[8], we[8];
            #pragma unroll
            for (int j = 0; j < 8; ++j)
                xt[j] = *(const float4*)(&xs[(tg + 4 * j) * XWSTR + kk]);
            #pragma unroll
            for (int m = 0; m < 8; ++m)
                we[m] = *(const float4*)(&ws[(eg + 8 * m) * XWSTR + kk]);
            #pragma unroll
            for (int j = 0; j < 8; ++j)
                #pragma unroll
                for (int m = 0; m < 8; ++m) {
                    acc[j][m] = fmaf(xt[j].x, we[m].x, acc[j][m]);
                    acc[j][m] = fmaf(xt[j].y, we[m].y, acc[j][m]);
                    acc[j][m] = fmaf(xt[j].z, we[m].z, acc[j][m]);
                    acc[j][m] = fmaf(xt[j].w, we[m].w, acc[j][m]);
                }
        }
        __syncthreads();
    }

    // ---- reduce 16 k-slices through LDS ----
    float* part = smem;                 // [8][32][PSTR]
    float* lgt  = smem + 8 * 32 * PSTR; // [32][PSTR]
    if (sl >= 8) {
        #pragma unroll
        for (int j = 0; j < 8; ++j)
            #pragma unroll
            for (int m = 0; m < 8; ++m)
                part[((sl - 8) * 32 + tg + 4 * j) * PSTR + eg + 8 * m] = acc[j][m];
    }
    __syncthreads();
    if (sl < 8) {
        #pragma unroll
        for (int j = 0; j < 8; ++j)
            #pragma unroll
            for (int m = 0; m < 8; ++m) {
                int idx = (sl * 32 + tg + 4 * j) * PSTR + eg + 8 * m;
                part[idx] += acc[j][m];
            }
    }
    __syncthreads();

    {
        int t  = tid >> 4;
        int e0 = (tid & 15) << 2;
        float4 a = {0, 0, 0, 0};
        #pragma unroll
        for (int s2 = 0; s2 < 8; ++s2) {
            float4 p = *(const float4*)(&part[(s2 * 32 + t) * PSTR + e0]);
            a.x += p.x; a.y += p.y; a.z += p.z; a.w += p.w;
        }
        *(float4*)(&lgt[t * PSTR + e0]) = a;
    }
    __syncthreads();

    // ---- softmax + argmax: 8 waves x 4 rows, lane = expert ----
    const int lane = tid & 63;
    const int wv   = tid >> 6;
    float me_acc  = 0.0f;
    int   cnt_acc = 0;
    #pragma unroll
    for (int r4 = 0; r4 < 4; ++r4) {
        int row = wv * 4 + r4;
        float v = lgt[row * PSTR + lane];
        float m = v; int mi = lane;
        #pragma unroll
        for (int off = 32; off > 0; off >>= 1) {
            float om  = __shfl_xor(m, off);
            int   omi = __shfl_xor(mi, off);
            if (om > m || (om == m && omi < mi)) { m = om; mi = omi; }
        }
        float ex = __expf(v - m);
        float sm = ex;
        #pragma unroll
        for (int off = 32; off > 0; off >>= 1) sm += __shfl_xor(sm, off);
        me_acc += ex / sm;
        if (lane == mi) {
            expert_idx[tok0 + row] = mi;
            gate_top[tok0 + row]   = 1.0f / sm;
            exp_s[row] = mi;
            ++cnt_acc;
        }
    }
    me_w[wv * NEXP + lane]  = me_acc;
    cnt_w[wv * NEXP + lane] = cnt_acc;
    __syncthreads();

    if (tid < 32) {   // within-tile rank (token order)
        int e = exp_s[tid];
        int rk = 0;
        for (int u = 0; u < tid; ++u) rk += (exp_s[u] == e) ? 1 : 0;
        rank[tok0 + tid] = rk;
    }
    if (tid < NEXP) {
        float ms = 0.f; int cs = 0;
        #pragma unroll
        for (int w = 0; w < 8; ++w) { ms += me_w[w * NEXP + tid]; cs += cnt_w[w * NEXP + tid]; }
        me_partial[gb * NEXP + tid] = ms;
        counts[gb * NEXP + tid]     = cs;
    }
}

// ---- 2. prefix + l_aux + direct scatter (R7/R9, unchanged) ----
__global__ __launch_bounds__(1024) void prefix_laux(
    const float* __restrict__ me_partial, const int* __restrict__ counts,
    const int* __restrict__ expert_idx, const int* __restrict__ rank,
    const float* __restrict__ gate_top, float* __restrict__ out)
{
    __shared__ int   bo_l[NTILE * NEXP];   // 64 KB exclusive offsets
    __shared__ int   cnt_l[16 * NEXP];
    __shared__ float me_l[16 * NEXP];
    __shared__ int   cnt_tot[NEXP];
    __shared__ float me_tot[NEXP];

    const int tid = threadIdx.x;
    const int e   = tid & 63;
    const int g   = tid >> 6;          // 0..15

    int cs = 0; float ms = 0.f;
    #pragma unroll
    for (int i = 0; i < 16; ++i) {
        int t = g * 16 + i;
        cs += counts[t * NEXP + e];
        ms += me_partial[t * NEXP + e];
    }
    cnt_l[g * NEXP + e] = cs;
    me_l[g * NEXP + e]  = ms;
    __syncthreads();

    if (g == 0) {
        int run = 0; float mt = 0.f;
        #pragma unroll
        for (int i = 0; i < 16; ++i) {
            int c = cnt_l[i * NEXP + e];
            cnt_l[i * NEXP + e] = run;
            run += c;
            mt  += me_l[i * NEXP + e];
        }
        cnt_tot[e] = run;
        me_tot[e]  = mt;
    }
    __syncthreads();

    int run = cnt_l[g * NEXP + e];
    #pragma unroll
    for (int i = 0; i < 16; ++i) {
        int t = g * 16 + i;
        bo_l[t * NEXP + e] = run;
        run += counts[t * NEXP + e];
    }
    __syncthreads();

    if (tid < NEXP) {
        float v = (me_tot[e] / (float)NTOK) * ((float)cnt_tot[e] / (float)NTOK);
        #pragma unroll
        for (int off = 32; off > 0; off >>= 1) v += __shfl_xor(v, off);
        if (e == 0) out[0] = v * (float)NEXP;   // mean(me*ce)*E*E == sum*E
    }

    #pragma unroll
    for (int ii = 0; ii < 8; ++ii) {           // direct scatter of nonzeros
        int s  = tid + (ii << 10);
        int ex = expert_idx[s];
        int loc = bo_l[(s >> 5) * NEXP + ex] + rank[s];
        if (loc < CAP) {
            size_t off = 1 + (size_t)s * (NEXP * CAP) + (size_t)ex * CAP + loc;
            out[off]              = gate_top[s];   // combine
            out[off + (size_t)RF] = 1.0f;          // dispatch
        }
    }
}

extern "C" void kernel_launch(void* const* d_in, const int* in_sizes, int n_in,
                              void* d_out, int out_size, void* d_ws, size_t ws_size,
                              hipStream_t stream)
{
    const float* x  = (const float*)d_in[0];
    const float* wg = (const float*)d_in[1];
    float* out = (float*)d_out;

    char* ws = (char*)d_ws;
    int*   expert_idx = (int*)  (ws);             // 32 KB
    float* gate_top   = (float*)(ws + 32768);     // 32 KB
    int*   rank       = (int*)  (ws + 65536);     // 32 KB
    float* me_partial = (float*)(ws + 98304);     // 64 KB
    int*   counts     = (int*)  (ws + 163840);    // 64 KB  (total 224 KB)

    gate_fill<<<NTILE, 512, 0, stream>>>(x, wg, out, expert_idx, gate_top,
                                         rank, me_partial, counts);
    prefix_laux<<<1, 1024, 0, stream>>>(me_partial, counts, expert_idx, rank,
                                        gate_top, out);
}